// Round 4
// baseline (575.845 us; speedup 1.0000x reference)
//
#include <hip/hip_runtime.h>
#include <hip/hip_bf16.h>

typedef __attribute__((ext_vector_type(8))) short bf16x8;
typedef __attribute__((ext_vector_type(4))) float f32x4;

#define GLDS(g, l) \
  __builtin_amdgcn_global_load_lds((const __attribute__((address_space(1))) void*)(g), \
                                   (__attribute__((address_space(3))) void*)(l), 16, 0, 0)

#define MFMA_BF16 __builtin_amdgcn_mfma_f32_16x16x32_bf16

// ---------------- Kernel 1: X fp32 -> bf16 (vectorized, grid-stride) ----------------
__global__ __launch_bounds__(256) void k_cvt_bf16(const float* __restrict__ x,
                                                  __hip_bfloat16* __restrict__ y,
                                                  long n8) {
  long stride = (long)gridDim.x * blockDim.x;
  for (long i = (long)blockIdx.x * blockDim.x + threadIdx.x; i < n8; i += stride) {
    const float4* xin = reinterpret_cast<const float4*>(x) + i * 2;
    float4 v0 = xin[0];
    float4 v1 = xin[1];
    union { __hip_bfloat16 h[8]; int4 v; } o;
    o.h[0] = __float2bfloat16(v0.x);
    o.h[1] = __float2bfloat16(v0.y);
    o.h[2] = __float2bfloat16(v0.z);
    o.h[3] = __float2bfloat16(v0.w);
    o.h[4] = __float2bfloat16(v1.x);
    o.h[5] = __float2bfloat16(v1.y);
    o.h[6] = __float2bfloat16(v1.z);
    o.h[7] = __float2bfloat16(v1.w);
    *reinterpret_cast<int4*>(y + i * 8) = o.v;
  }
}

// ---------------- Kernel 2: assemble W bf16 ----------------
__global__ __launch_bounds__(256) void k_make_w(const float* __restrict__ L,
                                                const float* __restrict__ R,
                                                __hip_bfloat16* __restrict__ W) {
  int o = blockIdx.x;
  int b = o & 63;
  __shared__ float Ls[512];
  Ls[threadIdx.x] = L[(size_t)o * 512 + threadIdx.x];
  Ls[threadIdx.x + 256] = L[(size_t)o * 512 + 256 + threadIdx.x];
  __syncthreads();
  for (int idx = threadIdx.x; idx < 4096; idx += 256) {
    int c = idx >> 6;
    int d = idx & 63;
    float s = 0.f;
#pragma unroll
    for (int r = 0; r < 8; ++r) {
      s += Ls[c * 8 + r] * R[(((size_t)(r * 64 + b) * 64 + c) << 6) + d];
    }
    W[(size_t)o * 4096 + idx] = __float2bfloat16(s);
  }
}

// ---------------- Kernel 3: 256x256 bf16 GEMM, frag-prefetch pipeline ----------------
// 4 phases per K-tile, ds_reads issued one phase ahead (drain under MFMA),
// ONE barrier per K-tile, counted lgkm/vmcnt waits. T1+T2+T5 retained.
__global__ __launch_bounds__(512, 2) void k_gemm_bt(const __hip_bfloat16* __restrict__ A,
                                                    const __hip_bfloat16* __restrict__ B,
                                                    const float* __restrict__ bias,
                                                    float* __restrict__ C) {
  const int K = 4096, N = 4096, NT = 64;
  __shared__ char lds[131072];
  char* const sAc = lds;          // 2 x 32768: A tile [256][64] bf16, swizzled
  char* const sBc = lds + 65536;  // 2 x 32768

  const int tid = threadIdx.x;
  const int lane = tid & 63;
  const int wid = tid >> 6;
  const int wr = wid >> 2;    // 0..1 (M half)
  const int wc = wid & 3;     // 0..3 (N quarter)

  // T1: bijective XCD swizzle (nwg = 1024, divisible by 8)
  const int orig = blockIdx.x;
  const int wg = (orig & 7) * 128 + (orig >> 3);
  const int gm0 = (wg >> 4) * 256;
  const int gn0 = (wg & 15) * 256;

  // ---- staging geometry (pre-swizzled global source, linear LDS dest) ----
  const int crow = tid >> 3;                              // row within 64-row group
  const int scol = ((tid & 7) << 4) ^ ((crow & 7) << 4);  // swizzled byte col
  const int voff = crow * 8192 + scol;                    // per-lane global byte offset
  const int wbase = (tid >> 6) << 10;                     // wave-uniform LDS chunk base
  const char* const Ab = (const char*)(A + (size_t)gm0 * K);
  const char* const Bb = (const char*)(B + (size_t)gn0 * K);

#define STAGEA(BUF, TS)                                                      \
  _Pragma("unroll")                                                          \
  for (int j = 0; j < 4; ++j)                                                \
    GLDS(Ab + (size_t)((TS) * 128 + j * 524288) + voff,                      \
         sAc + (BUF) * 32768 + j * 8192 + wbase);

#define STAGEB(BUF, TS)                                                      \
  _Pragma("unroll")                                                          \
  for (int j = 0; j < 4; ++j)                                                \
    GLDS(Bb + (size_t)((TS) * 128 + j * 524288) + voff,                      \
         sBc + (BUF) * 32768 + j * 8192 + wbase);

  // ---- fragment-read geometry (swizzled ds_read) ----
  const int lr = lane & 15;
  const int lk = lane >> 4;
  const int kx0 = (lk << 4) ^ ((lr & 7) << 4);
  const int kx1 = (64 + (lk << 4)) ^ ((lr & 7) << 4);
  const char* const rA0 = sAc + (((wr << 7) + lr) << 7) + kx0;
  const char* const rA1 = sAc + (((wr << 7) + lr) << 7) + kx1;
  const char* const rB0 = sBc + (((wc << 6) + lr) << 7) + kx0;
  const char* const rB1 = sBc + (((wc << 6) + lr) << 7) + kx1;

#define PREFA(DST, BUF, MOFS)                                                \
  _Pragma("unroll")                                                          \
  for (int m = 0; m < 4; ++m) {                                              \
    DST[m][0] = *(const bf16x8*)(rA0 + (BUF) * 32768 + ((MOFS) + m) * 2048); \
    DST[m][1] = *(const bf16x8*)(rA1 + (BUF) * 32768 + ((MOFS) + m) * 2048); \
  }

#define PREFB(DST, BUF, NOFS)                                                \
  _Pragma("unroll")                                                          \
  for (int n = 0; n < 2; ++n) {                                              \
    DST[n][0] = *(const bf16x8*)(rB0 + (BUF) * 32768 + ((NOFS) + n) * 2048); \
    DST[n][1] = *(const bf16x8*)(rB1 + (BUF) * 32768 + ((NOFS) + n) * 2048); \
  }

#define MFMA8X(AF, BF, MB, NB)                                               \
  _Pragma("unroll")                                                          \
  for (int m = 0; m < 4; ++m) {                                              \
    acc[(MB) + m][(NB) + 0] =                                                \
        MFMA_BF16(AF[m][0], BF[0][0], acc[(MB) + m][(NB) + 0], 0, 0, 0);     \
    acc[(MB) + m][(NB) + 0] =                                                \
        MFMA_BF16(AF[m][1], BF[0][1], acc[(MB) + m][(NB) + 0], 0, 0, 0);     \
    acc[(MB) + m][(NB) + 1] =                                                \
        MFMA_BF16(AF[m][0], BF[1][0], acc[(MB) + m][(NB) + 1], 0, 0, 0);     \
    acc[(MB) + m][(NB) + 1] =                                                \
        MFMA_BF16(AF[m][1], BF[1][1], acc[(MB) + m][(NB) + 1], 0, 0, 0);     \
  }

#define LGKM0 asm volatile("s_waitcnt lgkmcnt(0)" ::: "memory")
#define SBAR0 __builtin_amdgcn_sched_barrier(0)

  f32x4 acc[8][4];
#pragma unroll
  for (int m = 0; m < 8; ++m)
#pragma unroll
    for (int n = 0; n < 4; ++n) acc[m][n] = (f32x4){0.f, 0.f, 0.f, 0.f};

  bf16x8 aX[4][2], aY[4][2], b0[2][2], b2[2][2];

  // ---- prologue: stage tiles 0,1; read A03(0)+B01(0) ----
  STAGEA(0, 0) STAGEB(0, 0) STAGEA(1, 1) STAGEB(1, 1)
  asm volatile("s_waitcnt vmcnt(8)" ::: "memory");  // tile 0 landed
  SBAR0;
  __builtin_amdgcn_s_barrier();
  PREFA(aX, 0, 0) PREFB(b0, 0, 0)

  // Phase order per tile: P1(m03,n01,aX) P2(m47,n01,aY) P3(m03,n23,aX) P4(m47,n23,aY)
  // Prefetch: P1->aY=A47(t)  P2->b2=B23(t)  P3->b0=B01(t+1)  P4->aX=A03(t+1)
#define TILE(BUF, T)                                                         \
  {                                                                          \
    const int tS = ((T) + 2 < NT) ? (T) + 2 : NT - 1;                        \
    /* P1 */                                                                 \
    LGKM0; SBAR0;                                                            \
    PREFA(aY, BUF, 4)                                                        \
    SBAR0;                                                                   \
    __builtin_amdgcn_s_setprio(1);                                           \
    MFMA8X(aX, b0, 0, 0)                                                     \
    __builtin_amdgcn_s_setprio(0);                                           \
    /* P2 */                                                                 \
    LGKM0; SBAR0;                                                            \
    PREFB(b2, BUF, 2)                                                        \
    SBAR0;                                                                   \
    __builtin_amdgcn_s_setprio(1);                                           \
    MFMA8X(aY, b0, 4, 0)                                                     \
    __builtin_amdgcn_s_setprio(0);                                           \
    /* P3: the one barrier per tile */                                       \
    asm volatile("s_waitcnt lgkmcnt(0) vmcnt(0)" ::: "memory");              \
    SBAR0;                                                                   \
    __builtin_amdgcn_s_barrier();                                            \
    STAGEA(BUF, tS)                                                          \
    PREFB(b0, (BUF) ^ 1, 0)                                                  \
    SBAR0;                                                                   \
    __builtin_amdgcn_s_setprio(1);                                           \
    MFMA8X(aX, b2, 0, 2)                                                     \
    __builtin_amdgcn_s_setprio(0);                                           \
    /* P4 (no wait needed at entry) */                                       \
    SBAR0;                                                                   \
    STAGEB(BUF, tS)                                                          \
    PREFA(aX, (BUF) ^ 1, 0)                                                  \
    SBAR0;                                                                   \
    __builtin_amdgcn_s_setprio(1);                                           \
    MFMA8X(aY, b2, 4, 2)                                                     \
    __builtin_amdgcn_s_setprio(0);                                           \
  }

  for (int t = 0; t < NT; t += 2) {
    TILE(0, t)
    TILE(1, t + 1)
  }

  // ---- epilogue: C[row][col] = acc + bias[col] ----
  const int er = gm0 + (wr << 7) + ((lane >> 4) << 2);
  const int ec = gn0 + (wc << 6) + (lane & 15);
#pragma unroll
  for (int n = 0; n < 4; ++n) {
    const int c = ec + n * 16;
    const float bv = bias[c];
#pragma unroll
    for (int m = 0; m < 8; ++m) {
#pragma unroll
      for (int j = 0; j < 4; ++j) {
        C[(size_t)(er + m * 16 + j) * N + c] = acc[m][n][j] + bv;
      }
    }
  }
}

extern "C" void kernel_launch(void* const* d_in, const int* in_sizes, int n_in,
                              void* d_out, int out_size, void* d_ws, size_t ws_size,
                              hipStream_t stream) {
  const float* x = (const float*)d_in[0];     // [8,2048,4096]
  const float* L = (const float*)d_in[1];     // [64,64,64,8]
  const float* R = (const float*)d_in[2];     // [8,64,64,64]
  const float* bias = (const float*)d_in[3];  // [4096]
  float* out = (float*)d_out;                 // [16384,4096]

  __hip_bfloat16* Wb = (__hip_bfloat16*)d_ws;                                    // 33.5 MB
  __hip_bfloat16* Xb = (__hip_bfloat16*)((char*)d_ws + (size_t)4096 * 4096 * 2); // 134 MB

  const long n8 = (long)16384 * 4096 / 8;
  k_cvt_bf16<<<4096, 256, 0, stream>>>(x, Xb, n8);
  k_make_w<<<4096, 256, 0, stream>>>(L, R, Wb);

  dim3 grid(1024);  // (16384/256) * (4096/256)
  k_gemm_bt<<<grid, 512, 0, stream>>>(Xb, Wb, bias, out);
}